// Round 4
// baseline (601.785 us; speedup 1.0000x reference)
//
#include <hip/hip_runtime.h>
#include <stdint.h>

#define S_LEN 2048
#define NH 16
#define HD 64
#define CDIM 1024
#define QKV_LD 3072
#define WIN 256

typedef __attribute__((ext_vector_type(8))) short bf16x8;
typedef __attribute__((ext_vector_type(4))) short bf16x4;
typedef __attribute__((ext_vector_type(4))) float f32x4;

__device__ __forceinline__ short f2bf(float f) {
  uint32_t u = __builtin_bit_cast(uint32_t, f);
  u += 0x7fffu + ((u >> 16) & 1u);   // RNE
  return (short)(u >> 16);
}

// ---------------- fp32 -> bf16 conversion ----------------
__global__ void cvt_f32_bf16(const float* __restrict__ in, short* __restrict__ out, int n4) {
  int i = blockIdx.x * 256 + threadIdx.x;
  if (i >= n4) return;
  float4 v = ((const float4*)in)[i];
  bf16x4 o;
  o[0] = f2bf(v.x); o[1] = f2bf(v.y); o[2] = f2bf(v.z); o[3] = f2bf(v.w);
  ((bf16x4*)out)[i] = o;
}

// ---------------- async global->LDS helper ----------------
__device__ __forceinline__ void gl_lds16(const short* g, short* lds) {
  __builtin_amdgcn_global_load_lds(
      (const __attribute__((address_space(1))) uint32_t*)(uintptr_t)g,
      (__attribute__((address_space(3))) uint32_t*)(uintptr_t)lds,
      16, 0, 0);
}

#define WAITVM(N) asm volatile("s_waitcnt vmcnt(" #N ")" ::: "memory")

// ============ GEMM1: 256x384 tile, 12 waves, ring-4, 160KB LDS =============
// C[m][n] = A[m][k]*Bt[n][k] + bias[n], M=8192 N=3072 K=1024, bf16 out.
// Grid 256 blocks = 1 clean round. XCD swizzle m-fastest: each XCD owns one
// 384-col B-panel (768KB, L2-resident); A streams from L3.
// Per sub (K=32): 2 phases x 16 MFMA (wave-tile 128x64, acc[8][4]).
// Ring-4 slots; stage(j+3) split A@P0 / B@P1; per-wave-group counted vmcnt
// (waves 0-3 have an extra A chunk). Swizzle: 16B chunk ^= (row>>1)&3, applied
// inverse on the GLOBAL source (LDS linear), forward on ds_read. [r3-verified]
__global__ __launch_bounds__(768, 1) void gemm_big(
    const short* __restrict__ A, const short* __restrict__ Bt,
    const float* __restrict__ bias, short* __restrict__ Cout)
{
  constexpr int K = 1024, NSUB = 32, NN = 3072;
  __shared__ __align__(16) short Asm[4][256 * 32];   // 64KB
  __shared__ __align__(16) short Bsm[4][384 * 32];   // 96KB
  const int tid = threadIdx.x, wave = tid >> 6, lane = tid & 63;
  const int wm = wave / 6, wn = wave % 6;            // 2M x 6N wave grid
  const int cl = lane & 15, g = lane >> 4;

  const int bid = blockIdx.x;                        // 256 blocks, %8==0
  const int swzb = (bid & 7) * 32 + (bid >> 3);      // bijective XCD chunks
  const int m0 = (swzb & 31) * 256;                  // m fastest within XCD
  const int n0 = (swzb >> 5) * 384;                  // one n-panel per XCD

  // staging geometry: chunk c -> row c>>2, global col chunk (c&3)^((c>>3)&3)
  const int srow = tid >> 2;
  const int scc = (((tid & 3) ^ ((tid >> 3) & 3)) << 3);
  const short* aS0 = A  + (size_t)(m0 + srow) * K + scc;
  const short* aS1 = A  + (size_t)(m0 + 192 + srow) * K + scc;  // tid<256 only
  const short* bS0 = Bt + (size_t)(n0 + srow) * K + scc;
  const short* bS1 = Bt + (size_t)(n0 + 192 + srow) * K + scc;
  const int d0 = tid * 8, d1 = 6144 + tid * 8;

  auto stA = [&](int t) { const int s = t & 3;
    gl_lds16(aS0 + t * 32, &Asm[s][d0]);
    if (tid < 256) gl_lds16(aS1 + t * 32, &Asm[s][d1]);  // waves 0-3 only
  };
  auto stB = [&](int t) { const int s = t & 3;
    gl_lds16(bS0 + t * 32, &Bsm[s][d0]);
    gl_lds16(bS1 + t * 32, &Bsm[s][d1]);
  };

  const int rc = (g ^ ((cl >> 1) & 3)) << 3;
  const int arow = wm * 128 + cl;
  const int brow = wn * 64 + cl;

  bf16x8 aLo[4], aHi[4], b0v[4], b1v[4];
  f32x4 acc[8][4] = {};

#define RD_ALO(jj) if ((jj) < NSUB) { const int _s = (jj) & 3;                \
  _Pragma("unroll") for (int i = 0; i < 4; i++)                               \
    aLo[i] = *(const bf16x8*)&Asm[_s][(arow + i * 16) * 32 + rc]; }
#define RD_AHI(jj) { const int _s = (jj) & 3;                                 \
  _Pragma("unroll") for (int i = 0; i < 4; i++)                               \
    aHi[i] = *(const bf16x8*)&Asm[_s][(arow + 64 + i * 16) * 32 + rc]; }
#define RD_B(BB, jj) if ((jj) < NSUB) { const int _s = (jj) & 3;              \
  _Pragma("unroll") for (int n = 0; n < 4; n++)                               \
    BB[n] = *(const bf16x8*)&Bsm[_s][(brow + n * 16) * 32 + rc]; }
#define MFMAH(base, AA, BB)                                                   \
  __builtin_amdgcn_s_setprio(1);                                              \
  _Pragma("unroll") for (int i = 0; i < 4; i++)                               \
    _Pragma("unroll") for (int n = 0; n < 4; n++)                             \
      acc[(base) + i][n] = __builtin_amdgcn_mfma_f32_16x16x32_bf16(           \
          AA[i], BB[n], acc[(base) + i][n], 0, 0, 0);                         \
  __builtin_amdgcn_s_setprio(0);
#define WAITG() { if (wave < 4) { WAITVM(6); } else { WAITVM(4); } }

#define SUBP(jj, BC, BNx)                                                     \
  RD_AHI(jj);                                                                 \
  if ((jj) + 3 < NSUB) { stA((jj) + 3); WAITG(); } else { WAITVM(0); }        \
  __builtin_amdgcn_s_barrier();                                               \
  MFMAH(0, aLo, BC);                                                          \
  RD_ALO((jj) + 1); RD_B(BNx, (jj) + 1);                                      \
  if ((jj) + 3 < NSUB) { stB((jj) + 3); WAITG(); } else { WAITVM(0); }        \
  __builtin_amdgcn_s_barrier();                                               \
  MFMAH(4, aHi, BC);

  // prologue: subs 0,1,2 staged; retire sub 0 (w0-3: 12 in flight, w4-11: 9)
  stA(0); stB(0); stA(1); stB(1); stA(2); stB(2);
  if (wave < 4) { WAITVM(8); } else { WAITVM(6); }
  __builtin_amdgcn_s_barrier();
  RD_ALO(0); RD_B(b0v, 0);

  for (int j = 0; j < NSUB; j += 2) {
    SUBP(j, b0v, b1v);
    SUBP(j + 1, b1v, b0v);
  }
#undef RD_ALO
#undef RD_AHI
#undef RD_B
#undef MFMAH
#undef WAITG
#undef SUBP

  // epilogue: D-layout col=lane&15, row=(lane>>4)*4+e  [m89/m91]
#pragma unroll
  for (int n = 0; n < 4; n++) {
    const int col = n0 + wn * 64 + n * 16 + cl;
    const float bs = bias[col];
#pragma unroll
    for (int i = 0; i < 8; i++) {
      const int row = m0 + wm * 128 + i * 16 + g * 4;
#pragma unroll
      for (int e = 0; e < 4; e++)
        Cout[(size_t)(row + e) * NN + col] = f2bf(acc[i][n][e] + bs);
    }
  }
}

// ---------- ring-4 pipelined GEMM (r3-verified) — used for GEMM2 ------------
template <int BF16OUT>
__global__ __launch_bounds__(512) void gemm_ring(
    const short* __restrict__ A, const short* __restrict__ Bt,
    const float* __restrict__ bias, void* __restrict__ Cout, int N)
{
  constexpr int K = 1024;
  constexpr int NSUB = 32;
  __shared__ __align__(16) short Asm[4][128 * 32];
  __shared__ __align__(16) short Bsm[4][256 * 32];
  const int tid = threadIdx.x, wave = tid >> 6, lane = tid & 63;
  const int wm = wave >> 2, wn = wave & 3;
  const int cl = lane & 15, g = lane >> 4;

  const int gx = gridDim.x;
  const int nwg = gx * gridDim.y;
  const int flat = blockIdx.y * gx + blockIdx.x;
  const int swzb = (flat & 7) * (nwg >> 3) + (flat >> 3);
  const int m0 = (swzb / gx) * 128;
  const int n0 = (swzb % gx) * 256;

  const int srow = tid >> 2;
  const int scol = (((tid & 3) ^ ((tid >> 3) & 3)) << 3);
  const short* Asrc  = A + (size_t)(m0 + srow) * K + scol;
  const short* Bsrc0 = Bt + (size_t)(n0 + srow) * K + scol;
  const short* Bsrc1 = Bt + (size_t)(n0 + 128 + srow) * K + scol;
  const int ldso = tid * 8;

  auto stage = [&](int j) {
    const int st = j & 3;
    gl_lds16(Asrc  + j * 32, &Asm[st][ldso]);
    gl_lds16(Bsrc0 + j * 32, &Bsm[st][ldso]);
    gl_lds16(Bsrc1 + j * 32, &Bsm[st][4096 + ldso]);
  };

  const int rc = (g ^ ((cl >> 1) & 3)) << 3;
  const int arow = wm * 64 + cl;
  const int brow = wn * 64 + cl;

  f32x4 acc[4][4] = {};
  bf16x8 a0[4], b0[4], a1[4], b1[4];

  stage(0); stage(1); stage(2);
  WAITVM(3);
  __builtin_amdgcn_s_barrier();

#define READF(AA, BB, jj) { const int _s = (jj) & 3;                          \
  _Pragma("unroll") for (int i = 0; i < 4; i++)                               \
    AA[i] = *(const bf16x8*)&Asm[_s][(arow + i * 16) * 32 + rc];              \
  _Pragma("unroll") for (int n = 0; n < 4; n++)                               \
    BB[n] = *(const bf16x8*)&Bsm[_s][(brow + n * 16) * 32 + rc]; }

#define MFMA16(AA, BB)                                                        \
  __builtin_amdgcn_s_setprio(1);                                              \
  _Pragma("unroll") for (int i = 0; i < 4; i++)                               \
    _Pragma("unroll") for (int n = 0; n < 4; n++)                             \
      acc[i][n] = __builtin_amdgcn_mfma_f32_16x16x32_bf16(AA[i], BB[n], acc[i][n], 0, 0, 0); \
  __builtin_amdgcn_s_setprio(0);

  READF(a0, b0, 0);
  for (int j = 0; j < NSUB; j += 2) {
    READF(a1, b1, j + 1);
    if (j + 3 < NSUB) { stage(j + 3); WAITVM(3); } else { WAITVM(0); }
    __builtin_amdgcn_s_barrier();
    MFMA16(a0, b0);

    if (j + 2 < NSUB) READF(a0, b0, j + 2);
    if (j + 4 < NSUB) { stage(j + 4); WAITVM(3); } else { WAITVM(0); }
    __builtin_amdgcn_s_barrier();
    MFMA16(a1, b1);
  }
#undef READF
#undef MFMA16

#pragma unroll
  for (int n = 0; n < 4; n++) {
    const int col = n0 + wn * 64 + n * 16 + cl;
    const float bs = bias[col];
#pragma unroll
    for (int i = 0; i < 4; i++) {
      const int row = m0 + wm * 64 + i * 16 + g * 4;
#pragma unroll
      for (int e = 0; e < 4; e++) {
        const float v = acc[i][n][e] + bs;
        if (BF16OUT) ((short*)Cout)[(size_t)(row + e) * N + col] = f2bf(v);
        else         ((float*)Cout)[(size_t)(row + e) * N + col] = v;
      }
    }
  }
}

// ---------------- windowed causal flash attention (unchanged, verified) -----
__global__ __launch_bounds__(256) void attn_win(
    const short* __restrict__ qkv, short* __restrict__ ctx)
{
  const int tid = threadIdx.x;
  const int wave = tid >> 6, lane = tid & 63;
  const int grp = blockIdx.x % 32;
  const int h = (blockIdx.x / 32) % NH;
  const int b = blockIdx.x / (32 * NH);
  const int qb = (grp * 4 + wave) * 16;

  const int cl = lane & 15;
  const int g  = lane >> 4;

  const size_t rowQ = (size_t)(b * S_LEN + qb + cl) * QKV_LD + h * HD;
  bf16x8 qf0 = *(const bf16x8*)&qkv[rowQ + g * 8];
  bf16x8 qf1 = *(const bf16x8*)&qkv[rowQ + 32 + g * 8];

  float m_run = -1e30f, l_run = 0.f;
  f32x4 acc[4] = {};
  const f32x4 zero = {};

  const int kstart = qb >= WIN ? qb - WIN : 0;
  const int q_glob = qb + cl;

  for (int k0 = kstart; k0 <= qb; k0 += 16) {
    const size_t rowK = (size_t)(b * S_LEN + k0 + cl) * QKV_LD + CDIM + h * HD;
    bf16x8 kf0 = *(const bf16x8*)&qkv[rowK + g * 8];
    bf16x8 kf1 = *(const bf16x8*)&qkv[rowK + 32 + g * 8];
    f32x4 st = __builtin_amdgcn_mfma_f32_16x16x32_bf16(kf0, qf0, zero, 0, 0, 0);
    st = __builtin_amdgcn_mfma_f32_16x16x32_bf16(kf1, qf1, st, 0, 0, 0);

    float s[4]; bool ok[4];
    float mt = -1e30f;
#pragma unroll
    for (int e = 0; e < 4; e++) {
      int key = k0 + 4 * g + e;
      ok[e] = (key <= q_glob) && (q_glob - key < WIN);
      s[e] = st[e] * 0.125f;
      if (ok[e]) mt = fmaxf(mt, s[e]);
    }
    mt = fmaxf(mt, __shfl_xor(mt, 16, 64));
    mt = fmaxf(mt, __shfl_xor(mt, 32, 64));
    float m_new = fmaxf(m_run, mt);
    float scale = __expf(m_run - m_new);
    float p[4]; float ls = 0.f;
#pragma unroll
    for (int e = 0; e < 4; e++) {
      p[e] = ok[e] ? __expf(s[e] - m_new) : 0.f;
      ls += p[e];
    }
    ls += __shfl_xor(ls, 16, 64);
    ls += __shfl_xor(ls, 32, 64);
    l_run = l_run * scale + ls;
    m_run = m_new;
#pragma unroll
    for (int c = 0; c < 4; c++) acc[c] *= scale;

    bf16x4 pf;
#pragma unroll
    for (int e = 0; e < 4; e++) pf[e] = f2bf(p[e]);

    const size_t rowV = (size_t)(b * S_LEN + k0 + 4 * g) * QKV_LD + 2 * CDIM + h * HD + cl;
#pragma unroll
    for (int c = 0; c < 4; c++) {
      bf16x4 vf;
#pragma unroll
      for (int e = 0; e < 4; e++)
        vf[e] = qkv[rowV + (size_t)e * QKV_LD + c * 16];
      acc[c] = __builtin_amdgcn_mfma_f32_16x16x16bf16_1k(vf, pf, acc[c], 0, 0, 0);
    }
  }

  const float inv_l = 1.f / l_run;
  const size_t rowO = (size_t)(b * S_LEN + qb + cl) * CDIM + h * HD;
#pragma unroll
  for (int c = 0; c < 4; c++)
#pragma unroll
    for (int j = 0; j < 4; j++)
      ctx[rowO + c * 16 + 4 * g + j] = f2bf(acc[c][j] * inv_l);
}

// ---------------- launcher ----------------
extern "C" void kernel_launch(void* const* d_in, const int* in_sizes, int n_in,
                              void* d_out, int out_size, void* d_ws, size_t ws_size,
                              hipStream_t stream) {
  const float* x      = (const float*)d_in[0];
  const float* W_qkv  = (const float*)d_in[1];
  const float* b_qkv  = (const float*)d_in[2];
  const float* W_proj = (const float*)d_in[3];
  const float* b_proj = (const float*)d_in[4];
  float* out = (float*)d_out;

  const int BS = 4 * S_LEN;  // 8192 rows
  char* ws = (char*)d_ws;
  short* qkv_bf = (short*)ws;                              // [8192][3072] bf16
  short* x_bf   = (short*)(ws + (size_t)BS * QKV_LD * 2);  // [8192][1024]
  short* wq_bf  = x_bf + (size_t)BS * CDIM;                // [3072][1024]
  short* wp_bf  = wq_bf + (size_t)QKV_LD * CDIM;           // [1024][1024]
  short* ctx_bf = wp_bf + (size_t)CDIM * CDIM;             // [8192][1024]

  int n4 = BS * CDIM / 4;
  cvt_f32_bf16<<<(n4 + 255) / 256, 256, 0, stream>>>(x, x_bf, n4);
  n4 = QKV_LD * CDIM / 4;
  cvt_f32_bf16<<<(n4 + 255) / 256, 256, 0, stream>>>(W_qkv, wq_bf, n4);
  n4 = CDIM * CDIM / 4;
  cvt_f32_bf16<<<(n4 + 255) / 256, 256, 0, stream>>>(W_proj, wp_bf, n4);

  // GEMM1: 256x384 tiles, 32m x 8n = 256 blocks = 1 clean round
  gemm_big<<<256, 768, 0, stream>>>(x_bf, wq_bf, b_qkv, qkv_bf);

  attn_win<<<4 * NH * 32, 256, 0, stream>>>(qkv_bf, ctx_bf);

  dim3 g2(CDIM / 256, BS / 128);     // 4 x 64 = 256 blocks (1 clean round)
  gemm_ring<0><<<g2, 512, 0, stream>>>(ctx_bf, wp_bf, b_proj, out, CDIM);
}

// Round 5
// 271.394 us; speedup vs baseline: 2.2174x; 2.2174x over previous
//
#include <hip/hip_runtime.h>
#include <stdint.h>

#define S_LEN 2048
#define NH 16
#define HD 64
#define CDIM 1024
#define QKV_LD 3072
#define WIN 256

typedef __attribute__((ext_vector_type(8))) short bf16x8;
typedef __attribute__((ext_vector_type(4))) short bf16x4;
typedef __attribute__((ext_vector_type(4))) float f32x4;

__device__ __forceinline__ short f2bf(float f) {
  uint32_t u = __builtin_bit_cast(uint32_t, f);
  u += 0x7fffu + ((u >> 16) & 1u);   // RNE
  return (short)(u >> 16);
}

// ---------------- fp32 -> bf16 conversion ----------------
__global__ void cvt_f32_bf16(const float* __restrict__ in, short* __restrict__ out, int n4) {
  int i = blockIdx.x * 256 + threadIdx.x;
  if (i >= n4) return;
  float4 v = ((const float4*)in)[i];
  bf16x4 o;
  o[0] = f2bf(v.x); o[1] = f2bf(v.y); o[2] = f2bf(v.z); o[3] = f2bf(v.w);
  ((bf16x4*)out)[i] = o;
}

// ---------------- async global->LDS helper ----------------
__device__ __forceinline__ void gl_lds16(const short* g, short* lds) {
  __builtin_amdgcn_global_load_lds(
      (const __attribute__((address_space(1))) uint32_t*)(uintptr_t)g,
      (__attribute__((address_space(3))) uint32_t*)(uintptr_t)lds,
      16, 0, 0);
}

#define WAITVM(N) asm volatile("s_waitcnt vmcnt(" #N ")" ::: "memory")

// ============ GEMM1 (QKV): 256x384 tile, 12 waves, ring-4, 160KB LDS ========
// C[m][n] = A[m][k]*Bt[n][k] + bias[n], M=8192 N=3072 K=1024, bf16 out.
// Grid 256 blocks = 1 clean round; XCD x owns n-panel x (768KB, L2-resident).
// KEY r4 FIX: in-phase subtile reads (<=32 live frag VGPRs; r4's 128-reg
// cross-phase liveness spilled to scratch -> 1.9GB phantom HBM traffic).
// Per sub (K=32), slot s=j&3:
//   P0: ds_read A-lo(4)+B(4) | stageA(j+3) | BAR | lgkm0 | 16 MFMA acc[0..3] | BAR
//   P1: ds_read A-hi(4), B in-reg | stageB(j+3); vmcnt(8/4) | BAR | lgkm0 | 16 MFMA acc[4..7] | BAR
// Ring distance 3 = r3-proven hazard schedule. Swizzle = r3's (0 conflicts):
// 16B chunk ^= (row>>1)&3, inverse on GLOBAL source, forward on ds_read.
__global__ __launch_bounds__(768, 1) void gemm_qkv(
    const short* __restrict__ A, const short* __restrict__ Bt,
    const float* __restrict__ bias, short* __restrict__ Cout)
{
  constexpr int K = 1024, NSUB = 32, NN = 3072;
  __shared__ __align__(16) short Asm[4][256 * 32];   // 4 x 16KB
  __shared__ __align__(16) short Bsm[4][384 * 32];   // 4 x 24KB
  const int tid = threadIdx.x, wave = tid >> 6, lane = tid & 63;
  const int wm = wave / 6, wn = wave % 6;            // 2M x 6N wave grid
  const int cl = lane & 15, g = lane >> 4;

  const int bid = blockIdx.x;                        // 256 blocks
  const int swzb = (bid & 7) * 32 + (bid >> 3);      // XCD-chunked, bijective
  const int m0 = (swzb & 31) * 256;                  // m fastest within XCD
  const int n0 = (swzb >> 5) * 384;                  // one n-panel per XCD

  // staging: chunk c -> row c>>2, global col chunk (c&3)^((c>>3)&3) (inverse swz)
  const int srow = tid >> 2;
  const int scc = (((tid & 3) ^ ((tid >> 3) & 3)) << 3);
  const short* aS0 = A  + (size_t)(m0 + srow) * K + scc;        // rows 0..127 (tid<512)
  const short* aS1 = A  + (size_t)(m0 + 128 + srow) * K + scc;  // rows 128..255
  const short* bS0 = Bt + (size_t)(n0 + srow) * K + scc;        // rows 0..191
  const short* bS1 = Bt + (size_t)(n0 + 192 + srow) * K + scc;  // rows 192..383
  const int d8 = tid * 8;

  auto stageA = [&](int t) { const int s = t & 3;     // 2 loads, waves 0-7 only
    if (tid < 512) {
      gl_lds16(aS0 + t * 32, &Asm[s][d8]);
      gl_lds16(aS1 + t * 32, &Asm[s][4096 + d8]);
    }
  };
  auto stageB = [&](int t) { const int s = t & 3;     // 2 loads, all waves
    gl_lds16(bS0 + t * 32, &Bsm[s][d8]);
    gl_lds16(bS1 + t * 32, &Bsm[s][6144 + d8]);
  };

  const int rc = (g ^ ((cl >> 1) & 3)) << 3;          // read-side swizzled chunk
  const int arow = wm * 128 + cl;
  const int brow = wn * 64 + cl;

  f32x4 acc[8][4] = {};

  // prologue: subs 0,1,2; retire sub 0 (w0-7: 12 outstanding, w8-11: 6)
  stageA(0); stageB(0); stageA(1); stageB(1); stageA(2); stageB(2);
  if (wave < 8) { WAITVM(8); } else { WAITVM(4); }
  __builtin_amdgcn_s_barrier();

  for (int j = 0; j < NSUB; ++j) {
    const int s = j & 3;
    bf16x8 afr[4], bfr[4];

    // ---- P0: A-lo + B, MFMA acc[0..3] ----
#pragma unroll
    for (int i = 0; i < 4; i++)
      afr[i] = *(const bf16x8*)&Asm[s][(arow + i * 16) * 32 + rc];
#pragma unroll
    for (int n = 0; n < 4; n++)
      bfr[n] = *(const bf16x8*)&Bsm[s][(brow + n * 16) * 32 + rc];
    if (j + 3 < NSUB) stageA(j + 3);
    __builtin_amdgcn_s_barrier();
    asm volatile("s_waitcnt lgkmcnt(0)" ::: "memory");
    __builtin_amdgcn_sched_barrier(0);
    __builtin_amdgcn_s_setprio(1);
#pragma unroll
    for (int i = 0; i < 4; i++)
#pragma unroll
      for (int n = 0; n < 4; n++)
        acc[i][n] = __builtin_amdgcn_mfma_f32_16x16x32_bf16(afr[i], bfr[n], acc[i][n], 0, 0, 0);
    __builtin_amdgcn_s_setprio(0);
    __builtin_amdgcn_s_barrier();

    // ---- P1: A-hi (B reused in-reg), MFMA acc[4..7] ----
#pragma unroll
    for (int i = 0; i < 4; i++)
      afr[i] = *(const bf16x8*)&Asm[s][(arow + 64 + i * 16) * 32 + rc];
    if (j + 3 < NSUB) {
      stageB(j + 3);
      if (wave < 8) { WAITVM(8); } else { WAITVM(4); }
    } else {
      WAITVM(0);
    }
    __builtin_amdgcn_s_barrier();
    asm volatile("s_waitcnt lgkmcnt(0)" ::: "memory");
    __builtin_amdgcn_sched_barrier(0);
    __builtin_amdgcn_s_setprio(1);
#pragma unroll
    for (int i = 0; i < 4; i++)
#pragma unroll
      for (int n = 0; n < 4; n++)
        acc[4 + i][n] = __builtin_amdgcn_mfma_f32_16x16x32_bf16(afr[i], bfr[n], acc[4 + i][n], 0, 0, 0);
    __builtin_amdgcn_s_setprio(0);
    __builtin_amdgcn_s_barrier();
  }

  // epilogue: D-layout col=lane&15, row=(lane>>4)*4+e  [m89/m91]
#pragma unroll
  for (int n = 0; n < 4; n++) {
    const int col = n0 + wn * 64 + n * 16 + cl;
    const float bs = bias[col];
#pragma unroll
    for (int i = 0; i < 8; i++) {
      const int row = m0 + wm * 128 + i * 16 + g * 4;
#pragma unroll
      for (int e = 0; e < 4; e++)
        Cout[(size_t)(row + e) * NN + col] = f2bf(acc[i][n][e] + bs);
    }
  }
}

// ---------- ring-4 pipelined GEMM (r3-verified) — used for GEMM2 ------------
template <int BF16OUT>
__global__ __launch_bounds__(512) void gemm_ring(
    const short* __restrict__ A, const short* __restrict__ Bt,
    const float* __restrict__ bias, void* __restrict__ Cout, int N)
{
  constexpr int K = 1024;
  constexpr int NSUB = 32;
  __shared__ __align__(16) short Asm[4][128 * 32];
  __shared__ __align__(16) short Bsm[4][256 * 32];
  const int tid = threadIdx.x, wave = tid >> 6, lane = tid & 63;
  const int wm = wave >> 2, wn = wave & 3;
  const int cl = lane & 15, g = lane >> 4;

  const int gx = gridDim.x;
  const int nwg = gx * gridDim.y;
  const int flat = blockIdx.y * gx + blockIdx.x;
  const int swzb = (flat & 7) * (nwg >> 3) + (flat >> 3);
  const int m0 = (swzb / gx) * 128;
  const int n0 = (swzb % gx) * 256;

  const int srow = tid >> 2;
  const int scol = (((tid & 3) ^ ((tid >> 3) & 3)) << 3);
  const short* Asrc  = A + (size_t)(m0 + srow) * K + scol;
  const short* Bsrc0 = Bt + (size_t)(n0 + srow) * K + scol;
  const short* Bsrc1 = Bt + (size_t)(n0 + 128 + srow) * K + scol;
  const int ldso = tid * 8;

  auto stage = [&](int j) {
    const int st = j & 3;
    gl_lds16(Asrc  + j * 32, &Asm[st][ldso]);
    gl_lds16(Bsrc0 + j * 32, &Bsm[st][ldso]);
    gl_lds16(Bsrc1 + j * 32, &Bsm[st][4096 + ldso]);
  };

  const int rc = (g ^ ((cl >> 1) & 3)) << 3;
  const int arow = wm * 64 + cl;
  const int brow = wn * 64 + cl;

  f32x4 acc[4][4] = {};
  bf16x8 a0[4], b0[4], a1[4], b1[4];

  stage(0); stage(1); stage(2);
  WAITVM(3);
  __builtin_amdgcn_s_barrier();

#define READF(AA, BB, jj) { const int _s = (jj) & 3;                          \
  _Pragma("unroll") for (int i = 0; i < 4; i++)                               \
    AA[i] = *(const bf16x8*)&Asm[_s][(arow + i * 16) * 32 + rc];              \
  _Pragma("unroll") for (int n = 0; n < 4; n++)                               \
    BB[n] = *(const bf16x8*)&Bsm[_s][(brow + n * 16) * 32 + rc]; }

#define MFMA16(AA, BB)                                                        \
  __builtin_amdgcn_s_setprio(1);                                              \
  _Pragma("unroll") for (int i = 0; i < 4; i++)                               \
    _Pragma("unroll") for (int n = 0; n < 4; n++)                             \
      acc[i][n] = __builtin_amdgcn_mfma_f32_16x16x32_bf16(AA[i], BB[n], acc[i][n], 0, 0, 0); \
  __builtin_amdgcn_s_setprio(0);

  READF(a0, b0, 0);
  for (int j = 0; j < NSUB; j += 2) {
    READF(a1, b1, j + 1);
    if (j + 3 < NSUB) { stage(j + 3); WAITVM(3); } else { WAITVM(0); }
    __builtin_amdgcn_s_barrier();
    MFMA16(a0, b0);

    if (j + 2 < NSUB) READF(a0, b0, j + 2);
    if (j + 4 < NSUB) { stage(j + 4); WAITVM(3); } else { WAITVM(0); }
    __builtin_amdgcn_s_barrier();
    MFMA16(a1, b1);
  }
#undef READF
#undef MFMA16

#pragma unroll
  for (int n = 0; n < 4; n++) {
    const int col = n0 + wn * 64 + n * 16 + cl;
    const float bs = bias[col];
#pragma unroll
    for (int i = 0; i < 4; i++) {
      const int row = m0 + wm * 64 + i * 16 + g * 4;
#pragma unroll
      for (int e = 0; e < 4; e++) {
        const float v = acc[i][n][e] + bs;
        if (BF16OUT) ((short*)Cout)[(size_t)(row + e) * N + col] = f2bf(v);
        else         ((float*)Cout)[(size_t)(row + e) * N + col] = v;
      }
    }
  }
}

// ---------------- windowed causal flash attention (unchanged, verified) -----
__global__ __launch_bounds__(256) void attn_win(
    const short* __restrict__ qkv, short* __restrict__ ctx)
{
  const int tid = threadIdx.x;
  const int wave = tid >> 6, lane = tid & 63;
  const int grp = blockIdx.x % 32;
  const int h = (blockIdx.x / 32) % NH;
  const int b = blockIdx.x / (32 * NH);
  const int qb = (grp * 4 + wave) * 16;

  const int cl = lane & 15;
  const int g  = lane >> 4;

  const size_t rowQ = (size_t)(b * S_LEN + qb + cl) * QKV_LD + h * HD;
  bf16x8 qf0 = *(const bf16x8*)&qkv[rowQ + g * 8];
  bf16x8 qf1 = *(const bf16x8*)&qkv[rowQ + 32 + g * 8];

  float m_run = -1e30f, l_run = 0.f;
  f32x4 acc[4] = {};
  const f32x4 zero = {};

  const int kstart = qb >= WIN ? qb - WIN : 0;
  const int q_glob = qb + cl;

  for (int k0 = kstart; k0 <= qb; k0 += 16) {
    const size_t rowK = (size_t)(b * S_LEN + k0 + cl) * QKV_LD + CDIM + h * HD;
    bf16x8 kf0 = *(const bf16x8*)&qkv[rowK + g * 8];
    bf16x8 kf1 = *(const bf16x8*)&qkv[rowK + 32 + g * 8];
    f32x4 st = __builtin_amdgcn_mfma_f32_16x16x32_bf16(kf0, qf0, zero, 0, 0, 0);
    st = __builtin_amdgcn_mfma_f32_16x16x32_bf16(kf1, qf1, st, 0, 0, 0);

    float s[4]; bool ok[4];
    float mt = -1e30f;
#pragma unroll
    for (int e = 0; e < 4; e++) {
      int key = k0 + 4 * g + e;
      ok[e] = (key <= q_glob) && (q_glob - key < WIN);
      s[e] = st[e] * 0.125f;
      if (ok[e]) mt = fmaxf(mt, s[e]);
    }
    mt = fmaxf(mt, __shfl_xor(mt, 16, 64));
    mt = fmaxf(mt, __shfl_xor(mt, 32, 64));
    float m_new = fmaxf(m_run, mt);
    float scale = __expf(m_run - m_new);
    float p[4]; float ls = 0.f;
#pragma unroll
    for (int e = 0; e < 4; e++) {
      p[e] = ok[e] ? __expf(s[e] - m_new) : 0.f;
      ls += p[e];
    }
    ls += __shfl_xor(ls, 16, 64);
    ls += __shfl_xor(ls, 32, 64);
    l_run = l_run * scale + ls;
    m_run = m_new;
#pragma unroll
    for (int c = 0; c < 4; c++) acc[c] *= scale;

    bf16x4 pf;
#pragma unroll
    for (int e = 0; e < 4; e++) pf[e] = f2bf(p[e]);

    const size_t rowV = (size_t)(b * S_LEN + k0 + 4 * g) * QKV_LD + 2 * CDIM + h * HD + cl;
#pragma unroll
    for (int c = 0; c < 4; c++) {
      bf16x4 vf;
#pragma unroll
      for (int e = 0; e < 4; e++)
        vf[e] = qkv[rowV + (size_t)e * QKV_LD + c * 16];
      acc[c] = __builtin_amdgcn_mfma_f32_16x16x16bf16_1k(vf, pf, acc[c], 0, 0, 0);
    }
  }

  const float inv_l = 1.f / l_run;
  const size_t rowO = (size_t)(b * S_LEN + qb + cl) * CDIM + h * HD;
#pragma unroll
  for (int c = 0; c < 4; c++)
#pragma unroll
    for (int j = 0; j < 4; j++)
      ctx[rowO + c * 16 + 4 * g + j] = f2bf(acc[c][j] * inv_l);
}

// ---------------- launcher ----------------
extern "C" void kernel_launch(void* const* d_in, const int* in_sizes, int n_in,
                              void* d_out, int out_size, void* d_ws, size_t ws_size,
                              hipStream_t stream) {
  const float* x      = (const float*)d_in[0];
  const float* W_qkv  = (const float*)d_in[1];
  const float* b_qkv  = (const float*)d_in[2];
  const float* W_proj = (const float*)d_in[3];
  const float* b_proj = (const float*)d_in[4];
  float* out = (float*)d_out;

  const int BS = 4 * S_LEN;  // 8192 rows
  char* ws = (char*)d_ws;
  short* qkv_bf = (short*)ws;                              // [8192][3072] bf16
  short* x_bf   = (short*)(ws + (size_t)BS * QKV_LD * 2);  // [8192][1024]
  short* wq_bf  = x_bf + (size_t)BS * CDIM;                // [3072][1024]
  short* wp_bf  = wq_bf + (size_t)QKV_LD * CDIM;           // [1024][1024]
  short* ctx_bf = wp_bf + (size_t)CDIM * CDIM;             // [8192][1024]

  int n4 = BS * CDIM / 4;
  cvt_f32_bf16<<<(n4 + 255) / 256, 256, 0, stream>>>(x, x_bf, n4);
  n4 = QKV_LD * CDIM / 4;
  cvt_f32_bf16<<<(n4 + 255) / 256, 256, 0, stream>>>(W_qkv, wq_bf, n4);
  n4 = CDIM * CDIM / 4;
  cvt_f32_bf16<<<(n4 + 255) / 256, 256, 0, stream>>>(W_proj, wp_bf, n4);

  // GEMM1: 256x384 tiles, 32m x 8n = 256 blocks = 1 clean round
  gemm_qkv<<<256, 768, 0, stream>>>(x_bf, wq_bf, b_qkv, qkv_bf);

  attn_win<<<4 * NH * 32, 256, 0, stream>>>(qkv_bf, ctx_bf);

  dim3 g2(CDIM / 256, BS / 128);     // 4 x 64 = 256 blocks (1 clean round)
  gemm_ring<0><<<g2, 512, 0, stream>>>(ctx_bf, wp_bf, b_proj, out, CDIM);
}

// Round 6
// 254.034 us; speedup vs baseline: 2.3689x; 1.0683x over previous
//
#include <hip/hip_runtime.h>
#include <stdint.h>

#define S_LEN 2048
#define NH 16
#define HD 64
#define CDIM 1024
#define QKV_LD 3072
#define WIN 256

typedef __attribute__((ext_vector_type(8))) short bf16x8;
typedef __attribute__((ext_vector_type(4))) short bf16x4;
typedef __attribute__((ext_vector_type(4))) float f32x4;

__device__ __forceinline__ short f2bf(float f) {
  uint32_t u = __builtin_bit_cast(uint32_t, f);
  u += 0x7fffu + ((u >> 16) & 1u);   // RNE
  return (short)(u >> 16);
}

// ---------------- fp32 -> bf16 conversion ----------------
__global__ void cvt_f32_bf16(const float* __restrict__ in, short* __restrict__ out, int n4) {
  int i = blockIdx.x * 256 + threadIdx.x;
  if (i >= n4) return;
  float4 v = ((const float4*)in)[i];
  bf16x4 o;
  o[0] = f2bf(v.x); o[1] = f2bf(v.y); o[2] = f2bf(v.z); o[3] = f2bf(v.w);
  ((bf16x4*)out)[i] = o;
}

// ---------------- async global->LDS helper ----------------
__device__ __forceinline__ void gl_lds16(const short* g, short* lds) {
  __builtin_amdgcn_global_load_lds(
      (const __attribute__((address_space(1))) uint32_t*)(uintptr_t)g,
      (__attribute__((address_space(3))) uint32_t*)(uintptr_t)lds,
      16, 0, 0);
}

#define WAITVM(N) asm volatile("s_waitcnt vmcnt(" #N ")" ::: "memory")

// ============ GEMM1 (QKV): 256x256 tile, 8 waves, ring-4, 128KB LDS =========
// C[m][n] = A[m][k]*Bt[n][k] + bias[n], M=8192 N=3072 K=1024, bf16 out.
// r5 lesson: 12 waves -> 170-reg budget -> spill (WRITE 89MB vs 48 ideal).
// Now 8 waves (2/SIMD, 256-reg budget): acc[8][4]=128 AGPR + <=48 frag VGPR
// + ~25 addr fits spill-free. Wave-tile 128x64 keeps reads/MFMA = 0.375.
// Ring-4 of K=32 subs, distance-3 prefetch, counted vmcnt(8) (r3-proven);
// swizzle: 16B chunk ^= (row>>1)&3, inverse on GLOBAL source, fwd on ds_read
// (r3-verified: 0 bank conflicts).
// Per sub, slot s=j&3 (4 stage loads/sub: 2A+2B):
//  P0: ds_read A-lo(4)+B(4) | stageA(j+3) | BAR | lgkm0 | 16 MFMA acc[0..3] | BAR
//  P1: ds_read A-hi(4), B in-reg | stageB(j+3); vmcnt(8) | BAR | lgkm0 | 16 MFMA acc[4..7] | BAR
__global__ __launch_bounds__(512, 2) void gemm_qkv(
    const short* __restrict__ A, const short* __restrict__ Bt,
    const float* __restrict__ bias, short* __restrict__ Cout)
{
  constexpr int K = 1024, NSUB = 32, NN = 3072;
  __shared__ __align__(16) short Asm[4][256 * 32];   // 4 x 16KB
  __shared__ __align__(16) short Bsm[4][256 * 32];   // 4 x 16KB
  const int tid = threadIdx.x, wave = tid >> 6, lane = tid & 63;
  const int wm = wave >> 2, wn = wave & 3;           // 2M x 4N wave grid
  const int cl = lane & 15, g = lane >> 4;

  const int bid = blockIdx.x;                        // 384 blocks = 8 XCD x 48
  const int swzb = (bid & 7) * 48 + (bid >> 3);      // bijective XCD chunks
  const int m0 = (swzb & 31) * 256;                  // m fastest within XCD
  const int n0 = (swzb >> 5) * 256;

  // staging: thread t -> row t>>2 (+128 for 2nd op), global chunk (t&3)^((t>>3)&3)
  const int srow = tid >> 2;
  const int scc = (((tid & 3) ^ ((tid >> 3) & 3)) << 3);
  const short* aS0 = A  + (size_t)(m0 + srow) * K + scc;
  const short* aS1 = A  + (size_t)(m0 + 128 + srow) * K + scc;
  const short* bS0 = Bt + (size_t)(n0 + srow) * K + scc;
  const short* bS1 = Bt + (size_t)(n0 + 128 + srow) * K + scc;
  const int d8 = tid * 8;

  auto stageA = [&](int t) { const int s = t & 3;
    gl_lds16(aS0 + t * 32, &Asm[s][d8]);
    gl_lds16(aS1 + t * 32, &Asm[s][4096 + d8]);
  };
  auto stageB = [&](int t) { const int s = t & 3;
    gl_lds16(bS0 + t * 32, &Bsm[s][d8]);
    gl_lds16(bS1 + t * 32, &Bsm[s][4096 + d8]);
  };

  const int rc = (g ^ ((cl >> 1) & 3)) << 3;         // read-side swizzled chunk
  const int arow = wm * 128 + cl;
  const int brow = wn * 64 + cl;

  f32x4 acc[8][4] = {};

  // prologue: subs 0,1,2 staged (12 loads); vmcnt(8) retires sub 0
  stageA(0); stageB(0); stageA(1); stageB(1); stageA(2); stageB(2);
  WAITVM(8);
  __builtin_amdgcn_s_barrier();

  for (int j = 0; j < NSUB; ++j) {
    const int s = j & 3;
    bf16x8 afr[4], bfr[4];

    // ---- P0: A-lo + B, MFMA acc[0..3] ----
#pragma unroll
    for (int i = 0; i < 4; i++)
      afr[i] = *(const bf16x8*)&Asm[s][(arow + i * 16) * 32 + rc];
#pragma unroll
    for (int n = 0; n < 4; n++)
      bfr[n] = *(const bf16x8*)&Bsm[s][(brow + n * 16) * 32 + rc];
    if (j + 3 < NSUB) stageA(j + 3);
    __builtin_amdgcn_s_barrier();
    asm volatile("s_waitcnt lgkmcnt(0)" ::: "memory");
    __builtin_amdgcn_sched_barrier(0);
    __builtin_amdgcn_s_setprio(1);
#pragma unroll
    for (int i = 0; i < 4; i++)
#pragma unroll
      for (int n = 0; n < 4; n++)
        acc[i][n] = __builtin_amdgcn_mfma_f32_16x16x32_bf16(afr[i], bfr[n], acc[i][n], 0, 0, 0);
    __builtin_amdgcn_s_setprio(0);
    __builtin_amdgcn_s_barrier();

    // ---- P1: A-hi (B reused in-reg), MFMA acc[4..7] ----
#pragma unroll
    for (int i = 0; i < 4; i++)
      afr[i] = *(const bf16x8*)&Asm[s][(arow + 64 + i * 16) * 32 + rc];
    if (j + 3 < NSUB) {
      stageB(j + 3);
      WAITVM(8);
    } else {
      WAITVM(0);
    }
    __builtin_amdgcn_s_barrier();
    asm volatile("s_waitcnt lgkmcnt(0)" ::: "memory");
    __builtin_amdgcn_sched_barrier(0);
    __builtin_amdgcn_s_setprio(1);
#pragma unroll
    for (int i = 0; i < 4; i++)
#pragma unroll
      for (int n = 0; n < 4; n++)
        acc[4 + i][n] = __builtin_amdgcn_mfma_f32_16x16x32_bf16(afr[i], bfr[n], acc[4 + i][n], 0, 0, 0);
    __builtin_amdgcn_s_setprio(0);
    __builtin_amdgcn_s_barrier();
  }

  // epilogue: D-layout col=lane&15, row=(lane>>4)*4+e  [m89/m91]
#pragma unroll
  for (int n = 0; n < 4; n++) {
    const int col = n0 + wn * 64 + n * 16 + cl;
    const float bs = bias[col];
#pragma unroll
    for (int i = 0; i < 8; i++) {
      const int row = m0 + wm * 128 + i * 16 + g * 4;
#pragma unroll
      for (int e = 0; e < 4; e++)
        Cout[(size_t)(row + e) * NN + col] = f2bf(acc[i][n][e] + bs);
    }
  }
}

// ---------- ring-4 pipelined GEMM (r3-verified) — used for GEMM2 ------------
template <int BF16OUT>
__global__ __launch_bounds__(512) void gemm_ring(
    const short* __restrict__ A, const short* __restrict__ Bt,
    const float* __restrict__ bias, void* __restrict__ Cout, int N)
{
  constexpr int K = 1024;
  constexpr int NSUB = 32;
  __shared__ __align__(16) short Asm[4][128 * 32];
  __shared__ __align__(16) short Bsm[4][256 * 32];
  const int tid = threadIdx.x, wave = tid >> 6, lane = tid & 63;
  const int wm = wave >> 2, wn = wave & 3;
  const int cl = lane & 15, g = lane >> 4;

  const int gx = gridDim.x;
  const int nwg = gx * gridDim.y;
  const int flat = blockIdx.y * gx + blockIdx.x;
  const int swzb = (flat & 7) * (nwg >> 3) + (flat >> 3);
  const int m0 = (swzb / gx) * 128;
  const int n0 = (swzb % gx) * 256;

  const int srow = tid >> 2;
  const int scol = (((tid & 3) ^ ((tid >> 3) & 3)) << 3);
  const short* Asrc  = A + (size_t)(m0 + srow) * K + scol;
  const short* Bsrc0 = Bt + (size_t)(n0 + srow) * K + scol;
  const short* Bsrc1 = Bt + (size_t)(n0 + 128 + srow) * K + scol;
  const int ldso = tid * 8;

  auto stage = [&](int j) {
    const int st = j & 3;
    gl_lds16(Asrc  + j * 32, &Asm[st][ldso]);
    gl_lds16(Bsrc0 + j * 32, &Bsm[st][ldso]);
    gl_lds16(Bsrc1 + j * 32, &Bsm[st][4096 + ldso]);
  };

  const int rc = (g ^ ((cl >> 1) & 3)) << 3;
  const int arow = wm * 64 + cl;
  const int brow = wn * 64 + cl;

  f32x4 acc[4][4] = {};
  bf16x8 a0[4], b0[4], a1[4], b1[4];

  stage(0); stage(1); stage(2);
  WAITVM(3);
  __builtin_amdgcn_s_barrier();

#define READF(AA, BB, jj) { const int _s = (jj) & 3;                          \
  _Pragma("unroll") for (int i = 0; i < 4; i++)                               \
    AA[i] = *(const bf16x8*)&Asm[_s][(arow + i * 16) * 32 + rc];              \
  _Pragma("unroll") for (int n = 0; n < 4; n++)                               \
    BB[n] = *(const bf16x8*)&Bsm[_s][(brow + n * 16) * 32 + rc]; }

#define MFMA16(AA, BB)                                                        \
  __builtin_amdgcn_s_setprio(1);                                              \
  _Pragma("unroll") for (int i = 0; i < 4; i++)                               \
    _Pragma("unroll") for (int n = 0; n < 4; n++)                             \
      acc[i][n] = __builtin_amdgcn_mfma_f32_16x16x32_bf16(AA[i], BB[n], acc[i][n], 0, 0, 0); \
  __builtin_amdgcn_s_setprio(0);

  READF(a0, b0, 0);
  for (int j = 0; j < NSUB; j += 2) {
    READF(a1, b1, j + 1);
    if (j + 3 < NSUB) { stage(j + 3); WAITVM(3); } else { WAITVM(0); }
    __builtin_amdgcn_s_barrier();
    MFMA16(a0, b0);

    if (j + 2 < NSUB) READF(a0, b0, j + 2);
    if (j + 4 < NSUB) { stage(j + 4); WAITVM(3); } else { WAITVM(0); }
    __builtin_amdgcn_s_barrier();
    MFMA16(a1, b1);
  }
#undef READF
#undef MFMA16

#pragma unroll
  for (int n = 0; n < 4; n++) {
    const int col = n0 + wn * 64 + n * 16 + cl;
    const float bs = bias[col];
#pragma unroll
    for (int i = 0; i < 4; i++) {
      const int row = m0 + wm * 64 + i * 16 + g * 4;
#pragma unroll
      for (int e = 0; e < 4; e++) {
        const float v = acc[i][n][e] + bs;
        if (BF16OUT) ((short*)Cout)[(size_t)(row + e) * N + col] = f2bf(v);
        else         ((float*)Cout)[(size_t)(row + e) * N + col] = v;
      }
    }
  }
}

// ---------------- windowed causal flash attention (unchanged, verified) -----
__global__ __launch_bounds__(256) void attn_win(
    const short* __restrict__ qkv, short* __restrict__ ctx)
{
  const int tid = threadIdx.x;
  const int wave = tid >> 6, lane = tid & 63;
  const int grp = blockIdx.x % 32;
  const int h = (blockIdx.x / 32) % NH;
  const int b = blockIdx.x / (32 * NH);
  const int qb = (grp * 4 + wave) * 16;

  const int cl = lane & 15;
  const int g  = lane >> 4;

  const size_t rowQ = (size_t)(b * S_LEN + qb + cl) * QKV_LD + h * HD;
  bf16x8 qf0 = *(const bf16x8*)&qkv[rowQ + g * 8];
  bf16x8 qf1 = *(const bf16x8*)&qkv[rowQ + 32 + g * 8];

  float m_run = -1e30f, l_run = 0.f;
  f32x4 acc[4] = {};
  const f32x4 zero = {};

  const int kstart = qb >= WIN ? qb - WIN : 0;
  const int q_glob = qb + cl;

  for (int k0 = kstart; k0 <= qb; k0 += 16) {
    const size_t rowK = (size_t)(b * S_LEN + k0 + cl) * QKV_LD + CDIM + h * HD;
    bf16x8 kf0 = *(const bf16x8*)&qkv[rowK + g * 8];
    bf16x8 kf1 = *(const bf16x8*)&qkv[rowK + 32 + g * 8];
    f32x4 st = __builtin_amdgcn_mfma_f32_16x16x32_bf16(kf0, qf0, zero, 0, 0, 0);
    st = __builtin_amdgcn_mfma_f32_16x16x32_bf16(kf1, qf1, st, 0, 0, 0);

    float s[4]; bool ok[4];
    float mt = -1e30f;
#pragma unroll
    for (int e = 0; e < 4; e++) {
      int key = k0 + 4 * g + e;
      ok[e] = (key <= q_glob) && (q_glob - key < WIN);
      s[e] = st[e] * 0.125f;
      if (ok[e]) mt = fmaxf(mt, s[e]);
    }
    mt = fmaxf(mt, __shfl_xor(mt, 16, 64));
    mt = fmaxf(mt, __shfl_xor(mt, 32, 64));
    float m_new = fmaxf(m_run, mt);
    float scale = __expf(m_run - m_new);
    float p[4]; float ls = 0.f;
#pragma unroll
    for (int e = 0; e < 4; e++) {
      p[e] = ok[e] ? __expf(s[e] - m_new) : 0.f;
      ls += p[e];
    }
    ls += __shfl_xor(ls, 16, 64);
    ls += __shfl_xor(ls, 32, 64);
    l_run = l_run * scale + ls;
    m_run = m_new;
#pragma unroll
    for (int c = 0; c < 4; c++) acc[c] *= scale;

    bf16x4 pf;
#pragma unroll
    for (int e = 0; e < 4; e++) pf[e] = f2bf(p[e]);

    const size_t rowV = (size_t)(b * S_LEN + k0 + 4 * g) * QKV_LD + 2 * CDIM + h * HD + cl;
#pragma unroll
    for (int c = 0; c < 4; c++) {
      bf16x4 vf;
#pragma unroll
      for (int e = 0; e < 4; e++)
        vf[e] = qkv[rowV + (size_t)e * QKV_LD + c * 16];
      acc[c] = __builtin_amdgcn_mfma_f32_16x16x16bf16_1k(vf, pf, acc[c], 0, 0, 0);
    }
  }

  const float inv_l = 1.f / l_run;
  const size_t rowO = (size_t)(b * S_LEN + qb + cl) * CDIM + h * HD;
#pragma unroll
  for (int c = 0; c < 4; c++)
#pragma unroll
    for (int j = 0; j < 4; j++)
      ctx[rowO + c * 16 + 4 * g + j] = f2bf(acc[c][j] * inv_l);
}

// ---------------- launcher ----------------
extern "C" void kernel_launch(void* const* d_in, const int* in_sizes, int n_in,
                              void* d_out, int out_size, void* d_ws, size_t ws_size,
                              hipStream_t stream) {
  const float* x      = (const float*)d_in[0];
  const float* W_qkv  = (const float*)d_in[1];
  const float* b_qkv  = (const float*)d_in[2];
  const float* W_proj = (const float*)d_in[3];
  const float* b_proj = (const float*)d_in[4];
  float* out = (float*)d_out;

  const int BS = 4 * S_LEN;  // 8192 rows
  char* ws = (char*)d_ws;
  short* qkv_bf = (short*)ws;                              // [8192][3072] bf16
  short* x_bf   = (short*)(ws + (size_t)BS * QKV_LD * 2);  // [8192][1024]
  short* wq_bf  = x_bf + (size_t)BS * CDIM;                // [3072][1024]
  short* wp_bf  = wq_bf + (size_t)QKV_LD * CDIM;           // [1024][1024]
  short* ctx_bf = wp_bf + (size_t)CDIM * CDIM;             // [8192][1024]

  int n4 = BS * CDIM / 4;
  cvt_f32_bf16<<<(n4 + 255) / 256, 256, 0, stream>>>(x, x_bf, n4);
  n4 = QKV_LD * CDIM / 4;
  cvt_f32_bf16<<<(n4 + 255) / 256, 256, 0, stream>>>(W_qkv, wq_bf, n4);
  n4 = CDIM * CDIM / 4;
  cvt_f32_bf16<<<(n4 + 255) / 256, 256, 0, stream>>>(W_proj, wp_bf, n4);

  // GEMM1: 256x256 tiles, 32m x 12n = 384 blocks
  gemm_qkv<<<384, 512, 0, stream>>>(x_bf, wq_bf, b_qkv, qkv_bf);

  attn_win<<<4 * NH * 32, 256, 0, stream>>>(qkv_bf, ctx_bf);

  dim3 g2(CDIM / 256, BS / 128);     // 4 x 64 = 256 blocks (1 clean round)
  gemm_ring<0><<<g2, 512, 0, stream>>>(ctx_bf, wp_bf, b_proj, out, CDIM);
}

// Round 7
// 233.685 us; speedup vs baseline: 2.5752x; 1.0871x over previous
//
#include <hip/hip_runtime.h>
#include <stdint.h>

#define S_LEN 2048
#define NH 16
#define HD 64
#define CDIM 1024
#define QKV_LD 3072
#define WIN 256

typedef __attribute__((ext_vector_type(8))) short bf16x8;
typedef __attribute__((ext_vector_type(4))) short bf16x4;
typedef __attribute__((ext_vector_type(4))) float f32x4;
typedef __attribute__((ext_vector_type(16))) float f32x16;
typedef __attribute__((ext_vector_type(4))) uint32_t u32x4;

__device__ __forceinline__ short f2bf(float f) {
  uint32_t u = __builtin_bit_cast(uint32_t, f);
  u += 0x7fffu + ((u >> 16) & 1u);   // RNE
  return (short)(u >> 16);
}
__device__ __forceinline__ uint32_t pk2(float lo, float hi) {
  return ((uint32_t)(uint16_t)f2bf(hi) << 16) | (uint16_t)f2bf(lo);
}

// ---------------- fp32 -> bf16 conversion ----------------
__global__ void cvt_f32_bf16(const float* __restrict__ in, short* __restrict__ out, int n4) {
  int i = blockIdx.x * 256 + threadIdx.x;
  if (i >= n4) return;
  float4 v = ((const float4*)in)[i];
  bf16x4 o;
  o[0] = f2bf(v.x); o[1] = f2bf(v.y); o[2] = f2bf(v.z); o[3] = f2bf(v.w);
  ((bf16x4*)out)[i] = o;
}

// ---------------- async global->LDS helper ----------------
__device__ __forceinline__ void gl_lds16(const short* g, short* lds) {
  __builtin_amdgcn_global_load_lds(
      (const __attribute__((address_space(1))) uint32_t*)(uintptr_t)g,
      (__attribute__((address_space(3))) uint32_t*)(uintptr_t)lds,
      16, 0, 0);
}

#define WAITVM(N) asm volatile("s_waitcnt vmcnt(" #N ")" ::: "memory")

// ---------- ring-4 pipelined GEMM (r3-verified, 70us@N=3072) ---------------
template <int BF16OUT>
__global__ __launch_bounds__(512) void gemm_ring(
    const short* __restrict__ A, const short* __restrict__ Bt,
    const float* __restrict__ bias, void* __restrict__ Cout, int N)
{
  constexpr int K = 1024;
  constexpr int NSUB = 32;
  __shared__ __align__(16) short Asm[4][128 * 32];
  __shared__ __align__(16) short Bsm[4][256 * 32];
  const int tid = threadIdx.x, wave = tid >> 6, lane = tid & 63;
  const int wm = wave >> 2, wn = wave & 3;
  const int cl = lane & 15, g = lane >> 4;

  const int gx = gridDim.x;
  const int nwg = gx * gridDim.y;
  const int flat = blockIdx.y * gx + blockIdx.x;
  const int swzb = (flat & 7) * (nwg >> 3) + (flat >> 3);
  const int m0 = (swzb / gx) * 128;
  const int n0 = (swzb % gx) * 256;

  const int srow = tid >> 2;
  const int scol = (((tid & 3) ^ ((tid >> 3) & 3)) << 3);
  const short* Asrc  = A + (size_t)(m0 + srow) * K + scol;
  const short* Bsrc0 = Bt + (size_t)(n0 + srow) * K + scol;
  const short* Bsrc1 = Bt + (size_t)(n0 + 128 + srow) * K + scol;
  const int ldso = tid * 8;

  auto stage = [&](int j) {
    const int st = j & 3;
    gl_lds16(Asrc  + j * 32, &Asm[st][ldso]);
    gl_lds16(Bsrc0 + j * 32, &Bsm[st][ldso]);
    gl_lds16(Bsrc1 + j * 32, &Bsm[st][4096 + ldso]);
  };

  const int rc = (g ^ ((cl >> 1) & 3)) << 3;
  const int arow = wm * 64 + cl;
  const int brow = wn * 64 + cl;

  f32x4 acc[4][4] = {};
  bf16x8 a0[4], b0[4], a1[4], b1[4];

  stage(0); stage(1); stage(2);
  WAITVM(3);
  __builtin_amdgcn_s_barrier();

#define READF(AA, BB, jj) { const int _s = (jj) & 3;                          \
  _Pragma("unroll") for (int i = 0; i < 4; i++)                               \
    AA[i] = *(const bf16x8*)&Asm[_s][(arow + i * 16) * 32 + rc];              \
  _Pragma("unroll") for (int n = 0; n < 4; n++)                               \
    BB[n] = *(const bf16x8*)&Bsm[_s][(brow + n * 16) * 32 + rc]; }

#define MFMA16(AA, BB)                                                        \
  __builtin_amdgcn_s_setprio(1);                                              \
  _Pragma("unroll") for (int i = 0; i < 4; i++)                               \
    _Pragma("unroll") for (int n = 0; n < 4; n++)                             \
      acc[i][n] = __builtin_amdgcn_mfma_f32_16x16x32_bf16(AA[i], BB[n], acc[i][n], 0, 0, 0); \
  __builtin_amdgcn_s_setprio(0);

  READF(a0, b0, 0);
  for (int j = 0; j < NSUB; j += 2) {
    READF(a1, b1, j + 1);
    if (j + 3 < NSUB) { stage(j + 3); WAITVM(3); } else { WAITVM(0); }
    __builtin_amdgcn_s_barrier();
    MFMA16(a0, b0);

    if (j + 2 < NSUB) READF(a0, b0, j + 2);
    if (j + 4 < NSUB) { stage(j + 4); WAITVM(3); } else { WAITVM(0); }
    __builtin_amdgcn_s_barrier();
    MFMA16(a1, b1);
  }
#undef READF
#undef MFMA16

#pragma unroll
  for (int n = 0; n < 4; n++) {
    const int col = n0 + wn * 64 + n * 16 + cl;
    const float bs = bias[col];
#pragma unroll
    for (int i = 0; i < 4; i++) {
      const int row = m0 + wm * 64 + i * 16 + g * 4;
#pragma unroll
      for (int e = 0; e < 4; e++) {
        const float v = acc[i][n][e] + bs;
        if (BF16OUT) ((short*)Cout)[(size_t)(row + e) * N + col] = f2bf(v);
        else         ((float*)Cout)[(size_t)(row + e) * N + col] = v;
      }
    }
  }
}

// ============ windowed causal flash attention, 32q/wave, 32x32 MFMA =========
// Swapped QK^T: S^T[key][q] = mfma32x32x16(K_frag, Q_frag) over D=64 (4 chunks).
// D-layout (m74/m101): lane(c32,h32) reg r -> row (r&3)+8*(r>>2)+4*h32, col c32
//   => each lane holds 16 scores for ONE query q=qb+c32 -> softmax reduce is
//   in-lane + one shfl_xor(32).
// Swapped PV: ctx^T[d][q] = mfma(V^T_frag, P^T_frag): query stays lane-local
//   (uniform online rescale). P^T built from p[] via bf16 pair-packing + 2
//   shfl_xor(32) per k-chunk (T12 pattern). V^T frags = 32 scalar loads/tile
//   (coalesced 64B per row across lanes), issued right after QK to hide latency.
// No LDS, no barriers; 4 independent waves/block.
__global__ __launch_bounds__(256) void attn_win32(
    const short* __restrict__ qkv, short* __restrict__ ctx)
{
  const int lane = threadIdx.x & 63;
  const int wave = threadIdx.x >> 6;
  const int c32 = lane & 31, h32 = lane >> 5;

  // XCD-chunked bijective swizzle: 8 (b,h) pairs per XCD (4MB KV per L2)
  const int bid = blockIdx.x;                 // 1024 blocks
  const int swz = (bid & 7) * 128 + (bid >> 3);
  const int grp = swz & 15;
  const int h = (swz >> 4) & 15;
  const int b = swz >> 8;
  const int qb = (grp * 4 + wave) * 32;
  const int q = qb + c32;

  const short* Qb = qkv + (size_t)(b * S_LEN) * QKV_LD + h * HD;
  const short* Kb = Qb + CDIM;
  const short* Vb = Qb + 2 * CDIM;

  // Q frags (B-operand): lane(c32,h32) elem e of chunk t = Q[qb+c32][16t+8h32+e]
  bf16x8 qf[4];
  {
    const short* qrow = Qb + (size_t)(qb + c32) * QKV_LD + 8 * h32;
#pragma unroll
    for (int t = 0; t < 4; t++) qf[t] = *(const bf16x8*)(qrow + 16 * t);
  }

  const int kstart = qb >= WIN ? qb - WIN : 0;
  // V scalar-load offsets (u32, element units): row kstart+8h32+e, col c32
  uint32_t offV[8];
#pragma unroll
  for (int e = 0; e < 8; e++)
    offV[e] = (uint32_t)(kstart + 8 * h32 + e) * QKV_LD + c32;

  float m_run = -1e30f, l_run = 0.f;
  f32x16 accLo = {}, accHi = {};

  for (int k0 = kstart; k0 <= qb; k0 += 32) {
    // ---- QK^T ----
    f32x16 st = {};
    {
      const short* krow = Kb + (size_t)(k0 + c32) * QKV_LD + 8 * h32;
#pragma unroll
      for (int t = 0; t < 4; t++) {
        bf16x8 kf = *(const bf16x8*)(krow + 16 * t);
        st = __builtin_amdgcn_mfma_f32_32x32x16_bf16(kf, qf[t], st, 0, 0, 0);
      }
    }

    // ---- V^T frags: issue early (latency hides under softmax VALU) ----
    // vXt_[e] = V[k0+16t+8h32+e][d], d = c32 (Lo) / 32+c32 (Hi)
    short vL0[8], vH0[8], vL1[8], vH1[8];
#pragma unroll
    for (int e = 0; e < 8; e++) {
      vL0[e] = Vb[offV[e]]; vH0[e] = Vb[offV[e] + 32];
      offV[e] += 16 * QKV_LD;
    }
#pragma unroll
    for (int e = 0; e < 8; e++) {
      vL1[e] = Vb[offV[e]]; vH1[e] = Vb[offV[e] + 32];
      offV[e] += 16 * QKV_LD;
    }

    // ---- online softmax (query q = qb+c32, lane-local) ----
    const int dq = q - k0;
    float p[16];
    float mt = -1e30f;
#pragma unroll
    for (int r = 0; r < 16; r++) {
      const int kk = (r & 3) + 8 * (r >> 2) + 4 * h32;
      const bool ok = (uint32_t)(dq - kk) < (uint32_t)WIN;  // 0<=q-key<WIN
      p[r] = ok ? st[r] * 0.125f : -1e30f;
      mt = fmaxf(mt, p[r]);
    }
    mt = fmaxf(mt, __shfl_xor(mt, 32, 64));
    const float m_new = fmaxf(m_run, mt);
    const float scale = __expf(m_run - m_new);
    float ls = 0.f;
#pragma unroll
    for (int r = 0; r < 16; r++) {
      p[r] = (p[r] > -1e29f) ? __expf(p[r] - m_new) : 0.f;  // masked -> 0 always
      ls += p[r];
    }
    ls += __shfl_xor(ls, 32, 64);
    l_run = l_run * scale + ls;
    m_run = m_new;
#pragma unroll
    for (int i = 0; i < 16; i++) { accLo[i] *= scale; accHi[i] *= scale; }

    // ---- P^T bf16 words: w[2u]=keys(8u+4h32+{0,1}), w[2u+1]=+{2,3} ----
    uint32_t w[8];
#pragma unroll
    for (int u = 0; u < 4; u++) {
      w[2 * u]     = pk2(p[4 * u],     p[4 * u + 1]);
      w[2 * u + 1] = pk2(p[4 * u + 2], p[4 * u + 3]);
    }

    // ---- PV: per k-chunk t (16 keys), B-frag needs keys 16t+8h32+{0..7} ----
#pragma unroll
    for (int t = 0; t < 2; t++) {
      const uint32_t a0 = w[4 * t], a1 = w[4 * t + 1];       // keys 16t+4h32+{0..3}
      const uint32_t b0 = w[4 * t + 2], b1 = w[4 * t + 3];   // keys 16t+8+4h32+{0..3}
      const uint32_t snd0 = h32 ? a0 : b0, snd1 = h32 ? a1 : b1;
      const uint32_t x0 = (uint32_t)__shfl_xor((int)snd0, 32, 64);
      const uint32_t x1 = (uint32_t)__shfl_xor((int)snd1, 32, 64);
      // h32=0 needs {16t+0..7} = [a0,a1, x0,x1]; h32=1 needs {16t+8..15} = [x0,x1, b0,b1]
      u32x4 bw;
      bw[0] = h32 ? x0 : a0;
      bw[1] = h32 ? x1 : a1;
      bw[2] = h32 ? b0 : x0;
      bw[3] = h32 ? b1 : x1;
      const bf16x8 pf = __builtin_bit_cast(bf16x8, bw);

      bf16x8 vlo, vhi;
#pragma unroll
      for (int e = 0; e < 8; e++) {
        vlo[e] = t == 0 ? vL0[e] : vL1[e];
        vhi[e] = t == 0 ? vH0[e] : vH1[e];
      }
      accLo = __builtin_amdgcn_mfma_f32_32x32x16_bf16(vlo, pf, accLo, 0, 0, 0);
      accHi = __builtin_amdgcn_mfma_f32_32x32x16_bf16(vhi, pf, accHi, 0, 0, 0);
    }
  }

  // ---- epilogue: ctx^T reg r -> d = (r&3)+8*(r>>2)+4h32 (+32 Hi), q = c32 ----
  const float inv_l = 1.f / l_run;
  short* orow = ctx + (size_t)(b * S_LEN + q) * CDIM + h * HD;
#pragma unroll
  for (int u = 0; u < 4; u++) {
    bf16x4 o;
#pragma unroll
    for (int j = 0; j < 4; j++) o[j] = f2bf(accLo[4 * u + j] * inv_l);
    *(bf16x4*)(orow + 8 * u + 4 * h32) = o;
#pragma unroll
    for (int j = 0; j < 4; j++) o[j] = f2bf(accHi[4 * u + j] * inv_l);
    *(bf16x4*)(orow + 32 + 8 * u + 4 * h32) = o;
  }
}

// ---------------- launcher ----------------
extern "C" void kernel_launch(void* const* d_in, const int* in_sizes, int n_in,
                              void* d_out, int out_size, void* d_ws, size_t ws_size,
                              hipStream_t stream) {
  const float* x      = (const float*)d_in[0];
  const float* W_qkv  = (const float*)d_in[1];
  const float* b_qkv  = (const float*)d_in[2];
  const float* W_proj = (const float*)d_in[3];
  const float* b_proj = (const float*)d_in[4];
  float* out = (float*)d_out;

  const int BS = 4 * S_LEN;  // 8192 rows
  char* ws = (char*)d_ws;
  short* qkv_bf = (short*)ws;                              // [8192][3072] bf16
  short* x_bf   = (short*)(ws + (size_t)BS * QKV_LD * 2);  // [8192][1024]
  short* wq_bf  = x_bf + (size_t)BS * CDIM;                // [3072][1024]
  short* wp_bf  = wq_bf + (size_t)QKV_LD * CDIM;           // [1024][1024]
  short* ctx_bf = wp_bf + (size_t)CDIM * CDIM;             // [8192][1024]

  int n4 = BS * CDIM / 4;
  cvt_f32_bf16<<<(n4 + 255) / 256, 256, 0, stream>>>(x, x_bf, n4);
  n4 = QKV_LD * CDIM / 4;
  cvt_f32_bf16<<<(n4 + 255) / 256, 256, 0, stream>>>(W_qkv, wq_bf, n4);
  n4 = CDIM * CDIM / 4;
  cvt_f32_bf16<<<(n4 + 255) / 256, 256, 0, stream>>>(W_proj, wp_bf, n4);

  // GEMM1: r3-proven gemm_ring, 12 x 64 = 768 blocks (3 clean rounds)
  dim3 g1(QKV_LD / 256, BS / 128);
  gemm_ring<1><<<g1, 512, 0, stream>>>(x_bf, wq_bf, b_qkv, qkv_bf, QKV_LD);

  // attention: 4*16*16 = 1024 blocks x 4 waves (32 queries each)
  attn_win32<<<1024, 256, 0, stream>>>(qkv_bf, ctx_bf);

  // GEMM2: 4 x 64 = 256 blocks (1 clean round)
  dim3 g2(CDIM / 256, BS / 128);
  gemm_ring<0><<<g2, 512, 0, stream>>>(ctx_bf, wp_bf, b_proj, out, CDIM);
}